// Round 13
// baseline (413.849 us; speedup 1.0000x reference)
//
#include <hip/hip_runtime.h>

#define HIDC 128
#define NGRAPH 64
#define EPSV 1e-5f

typedef __attribute__((ext_vector_type(8))) short bf16x8;
typedef __attribute__((ext_vector_type(4))) float f32x4;
typedef unsigned long long u64;

__device__ inline uint bf16_rne(float f) {
    uint u = __float_as_uint(f);
    return (u + 0x7fffu + ((u >> 16) & 1u)) >> 16;
}
__device__ inline uint pack2(float a, float b) { return bf16_rne(a) | (bf16_rne(b) << 16); }
__device__ inline float blo(uint v) { return __uint_as_float(v << 16); }
__device__ inline float bhi(uint v) { return __uint_as_float(v & 0xffff0000u); }

// ---------------- init: zero cntI + featsum, prep W (bf16 swizzled) ----------------

__global__ void k_init(int* __restrict__ cntI, float* __restrict__ featsum, int N,
                       const float* __restrict__ W1, const float* __restrict__ W2,
                       const float* __restrict__ W3, ushort* __restrict__ Wp,
                       int ngrid) {
    int b = blockIdx.x;
    if (b < ngrid) {
        int i = b * 256 + threadIdx.x;
        if (i < N) cntI[i] = 0;
        if (i < NGRAPH * HIDC) featsum[i] = 0.f;
    } else {
        int w = b - ngrid;   // 0..2
        const float* W = (w == 0) ? W1 : (w == 1) ? W2 : W3;
        char* dst = (char*)(Wp + w * 128 * 128);
        for (int idx = threadIdx.x; idx < 128 * 64; idx += 256) {
            int n = idx & 127, k2 = idx >> 7;
            float w0 = W[(2 * k2) * 128 + n];
            float w1 = W[(2 * k2 + 1) * 128 + n];
            int byte = (n << 8) + ((k2 << 2) ^ ((n & 7) << 4));
            *(uint*)(dst + byte) = pack2(w0, w1);
        }
    }
}

// ---------------- CSR build ----------------

__global__ void k_count(const int* __restrict__ ei, int E, int* __restrict__ cnt,
                        int* __restrict__ seq) {
    int e2 = (blockIdx.x * blockDim.x + threadIdx.x) * 2;
    if (e2 + 1 < E) {
        int2 d = *(const int2*)&ei[E + e2];
        int s0 = atomicAdd(&cnt[d.x], 1);
        int s1 = atomicAdd(&cnt[d.y], 1);
        *(int2*)&seq[e2] = make_int2(s0, s1);
    } else if (e2 < E) {
        seq[e2] = atomicAdd(&cnt[ei[E + e2]], 1);
    }
}

__global__ void k_scan1(const int* __restrict__ cnt, int* __restrict__ rp,
                        int* __restrict__ partial, int N) {
    const int tid = threadIdx.x;
    int base = blockIdx.x * 2048 + tid * 8;
    int v[8], pre[8];
    int tot = 0;
#pragma unroll
    for (int j = 0; j < 8; j++) {
        int idx = base + j;
        v[j] = (idx < N) ? cnt[idx] : 0;
        pre[j] = tot; tot += v[j];
    }
    __shared__ int ls[256];
    ls[tid] = tot; __syncthreads();
    for (int off = 1; off < 256; off <<= 1) {
        int add = (tid >= off) ? ls[tid - off] : 0;
        __syncthreads();
        ls[tid] += add;
        __syncthreads();
    }
    int excl = ls[tid] - tot;
#pragma unroll
    for (int j = 0; j < 8; j++) {
        int idx = base + j;
        if (idx < N) rp[idx] = excl + pre[j];
    }
    if (tid == 255) partial[blockIdx.x] = ls[255];
}

__global__ void k_scan3(int* __restrict__ rp,
                        const int* __restrict__ partial, const int* __restrict__ cnt,
                        float* __restrict__ dinv, int N, int E, int NCH) {
    __shared__ int soff;
    int tid = threadIdx.x;
    int chunk = blockIdx.x >> 3;              // 2048 / 256
    if (tid < 64) {
        int v = (tid < NCH && tid < chunk) ? partial[tid] : 0;
        for (int off = 1; off < 64; off <<= 1) v += __shfl_xor(v, off);
        if (tid == 0) soff = v;
    }
    __syncthreads();
    int i = blockIdx.x * blockDim.x + tid;
    if (i < N) {
        rp[i] += soff;
        dinv[i] = rsqrtf((float)(cnt[i] + 1));   // +1 self loop
    }
    if (i == 0) rp[N] = E;
}

// edata.x = src * 256 (byte offset into bf16 table row), edata.y = norm
__global__ void k_fill(const int* __restrict__ ei, int E, const float* __restrict__ dinv,
                       const int* __restrict__ rp, const int* __restrict__ seq,
                       int2* __restrict__ edata) {
    int e4 = (blockIdx.x * blockDim.x + threadIdx.x) * 4;
    if (e4 + 4 <= E) {
        int4 s = *(const int4*)&ei[e4];
        int4 d = *(const int4*)&ei[E + e4];
        int4 q = *(const int4*)&seq[e4];
        int p0 = rp[d.x] + q.x;
        int p1 = rp[d.y] + q.y;
        int p2 = rp[d.z] + q.z;
        int p3 = rp[d.w] + q.w;
        float w0 = dinv[s.x] * dinv[d.x];
        float w1 = dinv[s.y] * dinv[d.y];
        float w2 = dinv[s.z] * dinv[d.z];
        float w3 = dinv[s.w] * dinv[d.w];
        edata[p0] = make_int2(s.x << 8, __float_as_int(w0));
        edata[p1] = make_int2(s.y << 8, __float_as_int(w1));
        edata[p2] = make_int2(s.z << 8, __float_as_int(w2));
        edata[p3] = make_int2(s.w << 8, __float_as_int(w3));
    } else {
        for (int e = e4; e < E; ++e) {
            int s = ei[e], d = ei[E + e];
            int p = rp[d] + seq[e];
            edata[p] = make_int2(s << 8, __float_as_int(dinv[s] * dinv[d]));
        }
    }
}

// ---------------- layer 0 fused: agg(x) -> @W0 -> bias -> relu -> LN -> bf16 ----------------

__global__ void __launch_bounds__(256) k_l0(
    const float* __restrict__ x, const int2* __restrict__ edata,
    const int* __restrict__ rp, const float* __restrict__ dinv,
    const float* __restrict__ W0, const float* __restrict__ b0,
    const float* __restrict__ g0, const float* __restrict__ be0,
    uint* __restrict__ hA, int N)
{
    __shared__ float s[896];   // W0 512 | b 128 | g 128 | be 128
    int tid = threadIdx.x;
    for (int i = tid; i < 896; i += 256) {
        float v;
        if (i < 512) v = W0[i];
        else if (i < 640) v = b0[i - 512];
        else if (i < 768) v = g0[i - 640];
        else v = be0[i - 768];
        s[i] = v;
    }
    __syncthreads();

    int lane = tid & 63;
    int wv = tid >> 6;
    int ch = lane & 3, es = (lane >> 2) & 3;
    int node = blockIdx.x * 16 + wv * 4 + (lane >> 4);
    bool valid = (node < N);
    const char* xb = (const char*)x + ch * 4;

    // gather (2-deep pipelined, stride-4 slice)
    float acc = 0.f;
    if (valid) {
        int e1 = rp[node + 1];
        int e = rp[node] + es;
        if (e < e1) {
            int2 med = edata[e];
            e += 4;
            for (; e < e1; e += 4) {
                float xv = *(const float*)(xb + (((uint)med.x) >> 4));
                int2 nxt = edata[e];
                acc = fmaf(__int_as_float(med.y), xv, acc);
                med = nxt;
            }
            float xv = *(const float*)(xb + (((uint)med.x) >> 4));
            acc = fmaf(__int_as_float(med.y), xv, acc);
        }
    }
    acc += __shfl_xor(acc, 4);
    acc += __shfl_xor(acc, 8);
    if (valid && es == 0) {
        float di = dinv[node];
        acc = fmaf(di * di, x[(size_t)node * 4 + ch], acc);
    }
    int base = lane & ~15;
    float ax0 = __shfl(acc, base + 0);
    float ax1 = __shfl(acc, base + 1);
    float ax2 = __shfl(acc, base + 2);
    float ax3 = __shfl(acc, base + 3);

    // transform: 8 channels per lane
    int t = lane & 15;
    int c0 = t * 8;
    float v[8];
    float s1 = 0.f, s2 = 0.f;
#pragma unroll
    for (int j = 0; j < 8; ++j) {
        int c = c0 + j;
        float vv = ax0 * s[c] + ax1 * s[128 + c] + ax2 * s[256 + c] + ax3 * s[384 + c] + s[512 + c];
        vv = fmaxf(vv, 0.f);
        v[j] = vv; s1 += vv; s2 += vv * vv;
    }
#pragma unroll
    for (int off = 1; off < 16; off <<= 1) { s1 += __shfl_xor(s1, off); s2 += __shfl_xor(s2, off); }
    float mu = s1 * (1.f / 128.f), var = s2 * (1.f / 128.f) - mu * mu;
    float r = rsqrtf(var + EPSV);
    if (valid) {
        uint4 o;
        o.x = pack2((v[0] - mu) * r * s[640 + c0 + 0] + s[768 + c0 + 0],
                    (v[1] - mu) * r * s[640 + c0 + 1] + s[768 + c0 + 1]);
        o.y = pack2((v[2] - mu) * r * s[640 + c0 + 2] + s[768 + c0 + 2],
                    (v[3] - mu) * r * s[640 + c0 + 3] + s[768 + c0 + 3]);
        o.z = pack2((v[4] - mu) * r * s[640 + c0 + 4] + s[768 + c0 + 4],
                    (v[5] - mu) * r * s[640 + c0 + 5] + s[768 + c0 + 5]);
        o.w = pack2((v[6] - mu) * r * s[640 + c0 + 6] + s[768 + c0 + 6],
                    (v[7] - mu) * r * s[640 + c0 + 7] + s[768 + c0 + 7]);
        *(uint4*)&hA[(size_t)node * 64 + t * 4] = o;
    }
}

// ---------------- fused agg (quad-row gathers) -> @W -> bias -> relu -> LN -> table | pool ----------------
// 16 lanes per row, 16 B/lane: one wave-load services 4 edges; 2-deep pipeline
// holds 16 edges in flight. Metadata via per-group vector loads (no selects).
// Masked slots use m=0 -> gather row 0 with weight 0 (contributes nothing).

__global__ void __launch_bounds__(256) k_aggw(
    const uint* __restrict__ tmp,   // N x 64 (bf16x2) gather table
    const int2* __restrict__ edata, const int* __restrict__ rp,
    const float* __restrict__ dinv, const ushort* __restrict__ Wp,
    const float* __restrict__ bias, const float* __restrict__ gamma,
    const float* __restrict__ beta, uint* __restrict__ outp, int N,
    float* __restrict__ featsum, const int* __restrict__ batch)
{
    __shared__ char Asw[16 * 256];      // 4 KB agg tile, XOR-swizzled bf16
    __shared__ uint Cst[16 * 64];       // 4 KB output staging (bf16)
    __shared__ float red[128];
    __shared__ int bi[16];
    int tid = threadIdx.x;
    int wv = tid >> 6, lane = tid & 63;
    int nbase = blockIdx.x * 16;
    int l16 = lane & 15, g4 = lane >> 4;        // 4 groups x 16 lanes
    const char* tlq = (const char*)tmp + l16 * 16;
    int wv4 = __builtin_amdgcn_readfirstlane(wv * 4);

#define WTF(m) __int_as_float((int)((m) >> 32))
#define LD64V(i) (*(const u64*)&edata[i])
#define FMA8(m, v)                                                     \
    {                                                                  \
        float wgt = WTF(m);                                            \
        a0 = fmaf(wgt, blo((v).x), a0); a1 = fmaf(wgt, bhi((v).x), a1);\
        a2 = fmaf(wgt, blo((v).y), a2); a3 = fmaf(wgt, bhi((v).y), a3);\
        a4 = fmaf(wgt, blo((v).z), a4); a5 = fmaf(wgt, bhi((v).z), a5);\
        a6 = fmaf(wgt, blo((v).w), a6); a7 = fmaf(wgt, bhi((v).w), a7);\
    }
#define GQ(m) { uint4 vq = *(const uint4*)(tlq + (uint)(m)); FMA8(m, vq); }

    // phase A: gather 4 nodes per wave; 4 edges per wave-load
    for (int j = 0; j < 4; ++j) {
        int row = wv4 + j;
        int node = nbase + row;
        float a0 = 0.f, a1 = 0.f, a2 = 0.f, a3 = 0.f;
        float a4 = 0.f, a5 = 0.f, a6 = 0.f, a7 = 0.f;
        if (node < N) {
            int nu = __builtin_amdgcn_readfirstlane(node);
            int e0 = rp[nu], e1 = rp[nu + 1];
            float di = dinv[nu];
            float dd = di * di;
            u64 mself = ((u64)__float_as_uint(dd) << 32) | (uint)(nu << 8);

            // batch 0: group 0 = self loop, groups 1-3 = edges e0..e0+2
            {
                u64 m = (g4 == 0) ? mself
                        : ((e0 + g4 - 1 < e1) ? LD64V(e0 + g4 - 1) : 0);
                GQ(m);
            }
            int ep = e0 + 3;
            // main loop: 8 edges per iter, 2-deep pipeline (16 edges in flight)
            if (ep + 8 <= e1) {
                u64 ma = LD64V(ep + g4);
                u64 mb = LD64V(ep + 4 + g4);
                ep += 8;
                for (; ep + 8 <= e1; ep += 8) {
                    uint4 va = *(const uint4*)(tlq + (uint)ma);
                    uint4 vb = *(const uint4*)(tlq + (uint)mb);
                    u64 na = LD64V(ep + g4);
                    u64 nb = LD64V(ep + 4 + g4);
                    FMA8(ma, va); FMA8(mb, vb);
                    ma = na; mb = nb;
                }
                {
                    uint4 va = *(const uint4*)(tlq + (uint)ma);
                    uint4 vb = *(const uint4*)(tlq + (uint)mb);
                    FMA8(ma, va); FMA8(mb, vb);
                }
            }
            // tail: masked batches of 4
            for (; ep < e1; ep += 4) {
                u64 m = (ep + g4 < e1) ? LD64V(ep + g4) : 0;
                GQ(m);
            }
            // reduce across the 4 groups
            a0 += __shfl_xor(a0, 16); a1 += __shfl_xor(a1, 16);
            a2 += __shfl_xor(a2, 16); a3 += __shfl_xor(a3, 16);
            a4 += __shfl_xor(a4, 16); a5 += __shfl_xor(a5, 16);
            a6 += __shfl_xor(a6, 16); a7 += __shfl_xor(a7, 16);
            a0 += __shfl_xor(a0, 32); a1 += __shfl_xor(a1, 32);
            a2 += __shfl_xor(a2, 32); a3 += __shfl_xor(a3, 32);
            a4 += __shfl_xor(a4, 32); a5 += __shfl_xor(a5, 32);
            a6 += __shfl_xor(a6, 32); a7 += __shfl_xor(a7, 32);
        }
        if (lane < 16) {
            uint4 o;
            o.x = pack2(a0, a1);
            o.y = pack2(a2, a3);
            o.z = pack2(a4, a5);
            o.w = pack2(a6, a7);
            *(uint4*)(Asw + row * 256 + ((l16 * 16) ^ ((row & 7) << 4))) = o;
        }
    }
    __syncthreads();

    // phase B: 16x128 @ 128x128 MFMA — wave wv computes n-tiles {2wv, 2wv+1}
    int m = lane & 15, g = lane >> 4;
    bf16x8 a[4];
    int aswz = (m & 7) << 4;
#pragma unroll
    for (int kk = 0; kk < 4; ++kk)
        a[kk] = *(const bf16x8*)(Asw + m * 256 + ((kk * 64 + g * 16) ^ aswz));

    f32x4 acc[2];
    acc[0] = (f32x4){0.f, 0.f, 0.f, 0.f};
    acc[1] = (f32x4){0.f, 0.f, 0.f, 0.f};
#pragma unroll
    for (int t2 = 0; t2 < 2; ++t2) {
        int n = m + (2 * wv + t2) * 16;
        const char* wb = (const char*)Wp + (n << 8);
        int swz = (n & 7) << 4;
#pragma unroll
        for (int kk = 0; kk < 4; ++kk) {
            bf16x8 b = *(const bf16x8*)(wb + ((kk * 64 + g * 16) ^ swz));
            acc[t2] = __builtin_amdgcn_mfma_f32_16x16x32_bf16(a[kk], b, acc[t2], 0, 0, 0);
        }
    }

    // bias + relu, per-row partial sums
    float bc0 = bias[m + (2 * wv) * 16];
    float bc1 = bias[m + (2 * wv + 1) * 16];
    float vals0[4], vals1[4];
#pragma unroll
    for (int q = 0; q < 4; ++q) {
        float v0 = fmaxf(acc[0][q] + bc0, 0.f);
        float v1 = fmaxf(acc[1][q] + bc1, 0.f);
        vals0[q] = v0; vals1[q] = v1;
        float s1 = v0 + v1, s2 = v0 * v0 + v1 * v1;
#pragma unroll
        for (int off = 1; off < 16; off <<= 1) { s1 += __shfl_xor(s1, off); s2 += __shfl_xor(s2, off); }
        if (m == 0) {
            red[(g * 4 + q) * 4 + wv] = s1;
            red[64 + (g * 4 + q) * 4 + wv] = s2;
        }
    }
    __syncthreads();

    // phase C: LN -> bf16 staging
    float gc0 = gamma[m + (2 * wv) * 16],  gc1 = gamma[m + (2 * wv + 1) * 16];
    float be0 = beta[m + (2 * wv) * 16],   be1 = beta[m + (2 * wv + 1) * 16];
#pragma unroll
    for (int q = 0; q < 4; ++q) {
        int row = g * 4 + q;
        float s1 = red[row * 4] + red[row * 4 + 1] + red[row * 4 + 2] + red[row * 4 + 3];
        float s2 = red[64 + row * 4] + red[64 + row * 4 + 1] + red[64 + row * 4 + 2] + red[64 + row * 4 + 3];
        float mu = s1 * (1.f / 128.f), var = s2 * (1.f / 128.f) - mu * mu;
        float r = rsqrtf(var + EPSV);
        ((ushort*)Cst)[row * 128 + m + (2 * wv) * 16]     = (ushort)bf16_rne((vals0[q] - mu) * r * gc0 + be0);
        ((ushort*)Cst)[row * 128 + m + (2 * wv + 1) * 16] = (ushort)bf16_rne((vals1[q] - mu) * r * gc1 + be1);
    }
    __syncthreads();

    if (outp) {
#pragma unroll
        for (int rr = 0; rr < 4; ++rr) {
            int row = rr * 4 + wv;
            int node = nbase + row;
            if (node < N)
                outp[(size_t)node * 64 + lane] = Cst[row * 64 + lane];
        }
    }
    if (featsum) {
        if (tid < 16) {
            int node = nbase + tid;
            bi[tid] = (node < N) ? batch[node] : -1;
        }
        __syncthreads();
        int gmin = 0x7fffffff, gmax = -1;
#pragma unroll
        for (int r2 = 0; r2 < 16; ++r2) {
            int b = bi[r2];
            if (b >= 0) { gmin = min(gmin, b); gmax = max(gmax, b); }
        }
        if (tid < 128 && gmax >= 0) {
            for (int gg = gmin; gg <= gmax; ++gg) {
                float sv = 0.f; int cnt = 0;
#pragma unroll
                for (int r2 = 0; r2 < 16; ++r2) {
                    if (bi[r2] == gg) {
                        uint u = Cst[r2 * 64 + (tid >> 1)];
                        sv += (tid & 1) ? bhi(u) : blo(u);
                        cnt++;
                    }
                }
                if (cnt) atomicAdd(&featsum[gg * 128 + tid], sv);
            }
        }
    }
#undef WTF
#undef LD64V
#undef FMA8
#undef GQ
}

// ---------------- fused FC head, 1024 threads ----------------

__global__ void __launch_bounds__(1024) k_fc(const float* __restrict__ featsum,
        const int* __restrict__ batch, int N,
        const float* __restrict__ W1, const float* __restrict__ b1,
        const float* __restrict__ W2, const float* __restrict__ b2,
        const float* __restrict__ W3, const float* __restrict__ b3,
        float* __restrict__ out) {
    int g = blockIdx.x, tid = threadIdx.x;
    int wv = tid >> 6, lane = tid & 63;
    __shared__ float fr[128];
    __shared__ float z1s[1024];
    __shared__ float z2p[1024];
    __shared__ float z2s[256];
    __shared__ float red[32];
    __shared__ float red2[64];
    __shared__ int cnts;
    if (tid == 0) {
        int lo = 0, hi = N;
        while (lo < hi) { int mm = (lo + hi) >> 1; if (batch[mm] < g) lo = mm + 1; else hi = mm; }
        int st = lo; hi = N;
        while (lo < hi) { int mm = (lo + hi) >> 1; if (batch[mm] < g + 1) lo = mm + 1; else hi = mm; }
        cnts = lo - st;
    }
    __syncthreads();
    float inv = 1.f / fmaxf((float)cnts, 1.f);
    if (tid < 128) fr[tid] = featsum[g * 128 + tid] * inv;
    __syncthreads();

    // fc1: 1024 outputs, 1/thread, k=128
    float a1 = b1[tid];
#pragma unroll 8
    for (int k = 0; k < 128; ++k) a1 = fmaf(fr[k], W1[k * 1024 + tid], a1);
    float s1 = a1, s2 = a1 * a1;
#pragma unroll
    for (int off = 1; off < 64; off <<= 1) { s1 += __shfl_xor(s1, off); s2 += __shfl_xor(s2, off); }
    if (lane == 0) { red[wv] = s1; red[16 + wv] = s2; }
    __syncthreads();
    float t1 = 0.f, t2 = 0.f;
#pragma unroll
    for (int i = 0; i < 16; ++i) { t1 += red[i]; t2 += red[16 + i]; }
    float mu = t1 * (1.f / 1024.f), var = t2 * (1.f / 1024.f) - mu * mu;
    float r = rsqrtf(var + EPSV);
    z1s[tid] = fmaxf((a1 - mu) * r, 0.f);
    __syncthreads();

    // fc2: out = tid&255, k-slice = tid>>8 (256 k's each)
    int o2 = tid & 255, ks = tid >> 8;
    float a2 = (ks == 0) ? b2[o2] : 0.f;
    int kb = ks * 256;
#pragma unroll 8
    for (int k = 0; k < 256; ++k) a2 = fmaf(z1s[kb + k], W2[(kb + k) * 256 + o2], a2);
    z2p[tid] = a2;
    __syncthreads();

    float v2 = 0.f;
    if (tid < 256) {
        v2 = z2p[tid] + z2p[256 + tid] + z2p[512 + tid] + z2p[768 + tid];
        s1 = v2; s2 = v2 * v2;
#pragma unroll
        for (int off = 1; off < 64; off <<= 1) { s1 += __shfl_xor(s1, off); s2 += __shfl_xor(s2, off); }
        if (lane == 0) { red[wv] = s1; red[16 + wv] = s2; }
    }
    __syncthreads();
    if (tid < 256) {
        t1 = red[0] + red[1] + red[2] + red[3];
        t2 = red[16] + red[17] + red[18] + red[19];
        mu = t1 * (1.f / 256.f); var = t2 * (1.f / 256.f) - mu * mu;
        r = rsqrtf(var + EPSV);
        z2s[tid] = fmaxf((v2 - mu) * r, 0.f);
    }
    __syncthreads();

    // fc3: thread = (k = tid>>2, o = tid&3); W3[tid] coalesced
    {
        float p = z2s[tid >> 2] * W3[tid];
#pragma unroll
        for (int off = 4; off < 64; off <<= 1) p += __shfl_xor(p, off);
        if ((lane & 63) < 4) red2[wv * 4 + (lane & 3)] = p;
    }
    __syncthreads();
    if (tid < 4) {
        float a3 = b3[tid];
#pragma unroll
        for (int i = 0; i < 16; ++i) a3 += red2[i * 4 + tid];
        out[g * 4 + tid] = a3;
    }
}

// ---------------- launch ----------------

extern "C" void kernel_launch(void* const* d_in, const int* in_sizes, int n_in,
                              void* d_out, int out_size, void* d_ws, size_t ws_size,
                              hipStream_t stream) {
    const float* x    = (const float*)d_in[0];
    const int*   ei   = (const int*)d_in[1];
    const int*   batch= (const int*)d_in[2];
    const float* Wl[4]  = { (const float*)d_in[3], (const float*)d_in[7],  (const float*)d_in[11], (const float*)d_in[15] };
    const float* bl[4]  = { (const float*)d_in[4], (const float*)d_in[8],  (const float*)d_in[12], (const float*)d_in[16] };
    const float* gl[4]  = { (const float*)d_in[5], (const float*)d_in[9],  (const float*)d_in[13], (const float*)d_in[17] };
    const float* bel[4] = { (const float*)d_in[6], (const float*)d_in[10], (const float*)d_in[14], (const float*)d_in[18] };
    const float* fcW1 = (const float*)d_in[19];
    const float* fcb1 = (const float*)d_in[20];
    const float* fcW2 = (const float*)d_in[21];
    const float* fcb2 = (const float*)d_in[22];
    const float* fcW3 = (const float*)d_in[23];
    const float* fcb3 = (const float*)d_in[24];
    float* out = (float*)d_out;

    const int N = in_sizes[2];
    const int E = in_sizes[1] / 2;

    char* w = (char*)d_ws;
    auto alloc = [&](size_t bytes) -> char* {
        char* p = w; w += (bytes + 255) & ~(size_t)255; return p;
    };
    uint*   hA      = (uint*)  alloc((size_t)N * 64 * 4);   // bf16 N x 128
    uint*   hB      = (uint*)  alloc((size_t)N * 64 * 4);
    int2*   edata   = (int2*)  alloc((size_t)E * 8);
    int*    seq     = (int*)   alloc((size_t)E * 4);
    int*    rp      = (int*)   alloc((size_t)(N + 1) * 4);
    int*    cntI    = (int*)   alloc((size_t)N * 4);
    float*  dinv    = (float*) alloc((size_t)N * 4);
    int*    partial = (int*)   alloc(64 * 4);
    ushort* Wp      = (ushort*)alloc(3 * 128 * 128 * 2);
    float*  featsum = (float*) alloc(NGRAPH * HIDC * 4);

    const int NCH = (N + 2047) / 2048;
    int egrid2 = (E / 2 + 255) / 256;
    int egrid4 = (E / 4 + 256) / 256;
    int ngrid = (N + 255) / 256;

    k_init<<<ngrid + 3, 256, 0, stream>>>(cntI, featsum, N, Wl[1], Wl[2], Wl[3], Wp, ngrid);
    k_count<<<egrid2, 256, 0, stream>>>(ei, E, cntI, seq);
    k_scan1<<<NCH, 256, 0, stream>>>(cntI, rp, partial, N);
    k_scan3<<<ngrid, 256, 0, stream>>>(rp, partial, cntI, dinv, N, E, NCH);
    k_fill<<<egrid4, 256, 0, stream>>>(ei, E, dinv, rp, seq, edata);

    // layer 0 fused -> hA
    k_l0<<<(N + 15) / 16, 256, 0, stream>>>(x, edata, rp, dinv, Wl[0], bl[0], gl[0], bel[0], hA, N);

    // layers 1..3 fused; layer 3 pools (no table write)
    const int fgrid = (N + 15) / 16;
    k_aggw<<<fgrid, 256, 0, stream>>>(hA, edata, rp, dinv, Wp + 0 * 128 * 128,
                                      bl[1], gl[1], bel[1], hB, N, nullptr, batch);
    k_aggw<<<fgrid, 256, 0, stream>>>(hB, edata, rp, dinv, Wp + 1 * 128 * 128,
                                      bl[2], gl[2], bel[2], hA, N, nullptr, batch);
    k_aggw<<<fgrid, 256, 0, stream>>>(hA, edata, rp, dinv, Wp + 2 * 128 * 128,
                                      bl[3], gl[3], bel[3], nullptr, N, featsum, batch);

    k_fc<<<NGRAPH, 1024, 0, stream>>>(featsum, batch, N, fcW1, fcb1, fcW2, fcb2, fcW3, fcb3, out);
}

// Round 14
// 402.066 us; speedup vs baseline: 1.0293x; 1.0293x over previous
//
#include <hip/hip_runtime.h>

#define HIDC 128
#define NGRAPH 64
#define EPSV 1e-5f

typedef __attribute__((ext_vector_type(8))) short bf16x8;
typedef __attribute__((ext_vector_type(4))) float f32x4;
typedef unsigned long long u64;

__device__ inline uint bf16_rne(float f) {
    uint u = __float_as_uint(f);
    return (u + 0x7fffu + ((u >> 16) & 1u)) >> 16;
}
__device__ inline uint pack2(float a, float b) { return bf16_rne(a) | (bf16_rne(b) << 16); }
__device__ inline float blo(uint v) { return __uint_as_float(v << 16); }
__device__ inline float bhi(uint v) { return __uint_as_float(v & 0xffff0000u); }

// ---------------- init: zero cntI + featsum, prep W (bf16 swizzled) ----------------

__global__ void k_init(int* __restrict__ cntI, float* __restrict__ featsum, int N,
                       const float* __restrict__ W1, const float* __restrict__ W2,
                       const float* __restrict__ W3, ushort* __restrict__ Wp,
                       int ngrid) {
    int b = blockIdx.x;
    if (b < ngrid) {
        int i = b * 256 + threadIdx.x;
        if (i < N) cntI[i] = 0;
        if (i < NGRAPH * HIDC) featsum[i] = 0.f;
    } else {
        int w = b - ngrid;   // 0..2
        const float* W = (w == 0) ? W1 : (w == 1) ? W2 : W3;
        char* dst = (char*)(Wp + w * 128 * 128);
        for (int idx = threadIdx.x; idx < 128 * 64; idx += 256) {
            int n = idx & 127, k2 = idx >> 7;
            float w0 = W[(2 * k2) * 128 + n];
            float w1 = W[(2 * k2 + 1) * 128 + n];
            int byte = (n << 8) + ((k2 << 2) ^ ((n & 7) << 4));
            *(uint*)(dst + byte) = pack2(w0, w1);
        }
    }
}

// ---------------- CSR build ----------------

__global__ void k_count(const int* __restrict__ ei, int E, int* __restrict__ cnt,
                        int* __restrict__ seq) {
    int e4 = (blockIdx.x * blockDim.x + threadIdx.x) * 4;
    if (e4 + 4 <= E) {
        int4 d = *(const int4*)&ei[E + e4];
        int s0 = atomicAdd(&cnt[d.x], 1);
        int s1 = atomicAdd(&cnt[d.y], 1);
        int s2 = atomicAdd(&cnt[d.z], 1);
        int s3 = atomicAdd(&cnt[d.w], 1);
        *(int4*)&seq[e4] = make_int4(s0, s1, s2, s3);
    } else {
        for (int e = e4; e < E; ++e)
            seq[e] = atomicAdd(&cnt[ei[E + e]], 1);
    }
}

__global__ void k_scan1(const int* __restrict__ cnt, int* __restrict__ rp,
                        int* __restrict__ partial, int N) {
    const int tid = threadIdx.x;
    int base = blockIdx.x * 2048 + tid * 8;
    int v[8], pre[8];
    int tot = 0;
#pragma unroll
    for (int j = 0; j < 8; j++) {
        int idx = base + j;
        v[j] = (idx < N) ? cnt[idx] : 0;
        pre[j] = tot; tot += v[j];
    }
    __shared__ int ls[256];
    ls[tid] = tot; __syncthreads();
    for (int off = 1; off < 256; off <<= 1) {
        int add = (tid >= off) ? ls[tid - off] : 0;
        __syncthreads();
        ls[tid] += add;
        __syncthreads();
    }
    int excl = ls[tid] - tot;
#pragma unroll
    for (int j = 0; j < 8; j++) {
        int idx = base + j;
        if (idx < N) rp[idx] = excl + pre[j];
    }
    if (tid == 255) partial[blockIdx.x] = ls[255];
}

__global__ void k_scan3(int* __restrict__ rp,
                        const int* __restrict__ partial, const int* __restrict__ cnt,
                        float* __restrict__ dinv, int N, int E, int NCH) {
    __shared__ int soff;
    int tid = threadIdx.x;
    int chunk = blockIdx.x >> 3;              // 2048 / 256
    if (tid < 64) {
        int v = (tid < NCH && tid < chunk) ? partial[tid] : 0;
        for (int off = 1; off < 64; off <<= 1) v += __shfl_xor(v, off);
        if (tid == 0) soff = v;
    }
    __syncthreads();
    int i = blockIdx.x * blockDim.x + tid;
    if (i < N) {
        rp[i] += soff;
        dinv[i] = rsqrtf((float)(cnt[i] + 1));   // +1 self loop
    }
    if (i == 0) rp[N] = E;
}

// edata.x = src * 256 (byte offset into bf16 table row), edata.y = norm
__global__ void k_fill(const int* __restrict__ ei, int E, const float* __restrict__ dinv,
                       const int* __restrict__ rp, const int* __restrict__ seq,
                       int2* __restrict__ edata) {
    int e4 = (blockIdx.x * blockDim.x + threadIdx.x) * 4;
    if (e4 + 4 <= E) {
        int4 s = *(const int4*)&ei[e4];
        int4 d = *(const int4*)&ei[E + e4];
        int4 q = *(const int4*)&seq[e4];
        int p0 = rp[d.x] + q.x;
        int p1 = rp[d.y] + q.y;
        int p2 = rp[d.z] + q.z;
        int p3 = rp[d.w] + q.w;
        float w0 = dinv[s.x] * dinv[d.x];
        float w1 = dinv[s.y] * dinv[d.y];
        float w2 = dinv[s.z] * dinv[d.z];
        float w3 = dinv[s.w] * dinv[d.w];
        edata[p0] = make_int2(s.x << 8, __float_as_int(w0));
        edata[p1] = make_int2(s.y << 8, __float_as_int(w1));
        edata[p2] = make_int2(s.z << 8, __float_as_int(w2));
        edata[p3] = make_int2(s.w << 8, __float_as_int(w3));
    } else {
        for (int e = e4; e < E; ++e) {
            int s = ei[e], d = ei[E + e];
            int p = rp[d] + seq[e];
            edata[p] = make_int2(s << 8, __float_as_int(dinv[s] * dinv[d]));
        }
    }
}

// ---------------- layer 0 fused: agg(x) -> @W0 -> bias -> relu -> LN -> bf16 ----------------
// One edge per lane (x rows are 16 B): 16 edges in flight per node, 64/wave.

__global__ void __launch_bounds__(256) k_l0(
    const float* __restrict__ x, const int2* __restrict__ edata,
    const int* __restrict__ rp, const float* __restrict__ dinv,
    const float* __restrict__ W0, const float* __restrict__ b0,
    const float* __restrict__ g0, const float* __restrict__ be0,
    uint* __restrict__ hA, int N)
{
    __shared__ float s[896];   // W0 512 | b 128 | g 128 | be 128
    int tid = threadIdx.x;
    for (int i = tid; i < 896; i += 256) {
        float v;
        if (i < 512) v = W0[i];
        else if (i < 640) v = b0[i - 512];
        else if (i < 768) v = g0[i - 640];
        else v = be0[i - 768];
        s[i] = v;
    }
    __syncthreads();

    int lane = tid & 63;
    int wv = tid >> 6;
    int l16 = lane & 15;
    int node = blockIdx.x * 16 + wv * 4 + (lane >> 4);
    bool valid = (node < N);
    const char* xb = (const char*)x;

    // gather: lane l16 handles edges e0+l16, e0+l16+16, ... (2-deep pipelined)
    float ax0 = 0.f, ax1 = 0.f, ax2 = 0.f, ax3 = 0.f;
    if (valid) {
        int e1 = rp[node + 1];
        int e = rp[node] + l16;
        if (e < e1) {
            int2 med = edata[e];
            e += 16;
            for (; e < e1; e += 16) {
                float4 xv = *(const float4*)(xb + (((uint)med.x) >> 4));
                int2 nxt = edata[e];
                float wgt = __int_as_float(med.y);
                ax0 = fmaf(wgt, xv.x, ax0); ax1 = fmaf(wgt, xv.y, ax1);
                ax2 = fmaf(wgt, xv.z, ax2); ax3 = fmaf(wgt, xv.w, ax3);
                med = nxt;
            }
            float4 xv = *(const float4*)(xb + (((uint)med.x) >> 4));
            float wgt = __int_as_float(med.y);
            ax0 = fmaf(wgt, xv.x, ax0); ax1 = fmaf(wgt, xv.y, ax1);
            ax2 = fmaf(wgt, xv.z, ax2); ax3 = fmaf(wgt, xv.w, ax3);
        }
        if (l16 == 0) {   // self loop, counted once
            float di = dinv[node];
            float dd = di * di;
            float4 xv = *(const float4*)(xb + (size_t)node * 16);
            ax0 = fmaf(dd, xv.x, ax0); ax1 = fmaf(dd, xv.y, ax1);
            ax2 = fmaf(dd, xv.z, ax2); ax3 = fmaf(dd, xv.w, ax3);
        }
    }
    // 16-lane xor reduce: all lanes end with the node's 4-channel agg
#pragma unroll
    for (int off = 1; off < 16; off <<= 1) {
        ax0 += __shfl_xor(ax0, off); ax1 += __shfl_xor(ax1, off);
        ax2 += __shfl_xor(ax2, off); ax3 += __shfl_xor(ax3, off);
    }

    // transform: 8 channels per lane
    int c0 = l16 * 8;
    float v[8];
    float s1 = 0.f, s2 = 0.f;
#pragma unroll
    for (int j = 0; j < 8; ++j) {
        int c = c0 + j;
        float vv = ax0 * s[c] + ax1 * s[128 + c] + ax2 * s[256 + c] + ax3 * s[384 + c] + s[512 + c];
        vv = fmaxf(vv, 0.f);
        v[j] = vv; s1 += vv; s2 += vv * vv;
    }
#pragma unroll
    for (int off = 1; off < 16; off <<= 1) { s1 += __shfl_xor(s1, off); s2 += __shfl_xor(s2, off); }
    float mu = s1 * (1.f / 128.f), var = s2 * (1.f / 128.f) - mu * mu;
    float r = rsqrtf(var + EPSV);
    if (valid) {
        uint4 o;
        o.x = pack2((v[0] - mu) * r * s[640 + c0 + 0] + s[768 + c0 + 0],
                    (v[1] - mu) * r * s[640 + c0 + 1] + s[768 + c0 + 1]);
        o.y = pack2((v[2] - mu) * r * s[640 + c0 + 2] + s[768 + c0 + 2],
                    (v[3] - mu) * r * s[640 + c0 + 3] + s[768 + c0 + 3]);
        o.z = pack2((v[4] - mu) * r * s[640 + c0 + 4] + s[768 + c0 + 4],
                    (v[5] - mu) * r * s[640 + c0 + 5] + s[768 + c0 + 5]);
        o.w = pack2((v[6] - mu) * r * s[640 + c0 + 6] + s[768 + c0 + 6],
                    (v[7] - mu) * r * s[640 + c0 + 7] + s[768 + c0 + 7]);
        *(uint4*)&hA[(size_t)node * 64 + l16 * 4] = o;
    }
}

// ---------------- fused agg (paired-row gathers, r12-proven) -> @W -> LN -> table | pool ----------------

__global__ void __launch_bounds__(256) k_aggw(
    const uint* __restrict__ tmp,   // N x 64 (bf16x2) gather table
    const int2* __restrict__ edata, const int* __restrict__ rp,
    const float* __restrict__ dinv, const ushort* __restrict__ Wp,
    const float* __restrict__ bias, const float* __restrict__ gamma,
    const float* __restrict__ beta, uint* __restrict__ outp, int N,
    float* __restrict__ featsum, const int* __restrict__ batch)
{
    __shared__ char Asw[16 * 256];      // 4 KB agg tile, XOR-swizzled bf16
    __shared__ uint Cst[16 * 64];       // 4 KB output staging (bf16)
    __shared__ float red[128];
    __shared__ int bi[16];
    int tid = threadIdx.x;
    int wv = tid >> 6, lane = tid & 63;
    int nbase = blockIdx.x * 16;
    const char* tlb = (const char*)tmp + (lane & 31) * 8;
    const bool lowh = (lane < 32);
    int wv4 = __builtin_amdgcn_readfirstlane(wv * 4);

#define WTF(m) __int_as_float((int)((m) >> 32))
#define LD64(i) (*(const u64*)&edata[i])
#define PAIRF(ma, mb)                                                  \
    {                                                                  \
        uint off = lowh ? (uint)(ma) : (uint)(mb);                     \
        float wgt = lowh ? WTF(ma) : WTF(mb);                          \
        u64 v = *(const u64*)(tlb + off);                              \
        uint vl = (uint)v, vh = (uint)(v >> 32);                       \
        a0 = fmaf(wgt, blo(vl), a0); a1 = fmaf(wgt, bhi(vl), a1);      \
        a2 = fmaf(wgt, blo(vh), a2); a3 = fmaf(wgt, bhi(vh), a3);      \
    }
#define GFMA(ma, mb, v)                                                \
    {                                                                  \
        float wgt = lowh ? WTF(ma) : WTF(mb);                          \
        uint vl = (uint)(v), vh = (uint)((v) >> 32);                   \
        a0 = fmaf(wgt, blo(vl), a0); a1 = fmaf(wgt, bhi(vl), a1);      \
        a2 = fmaf(wgt, blo(vh), a2); a3 = fmaf(wgt, bhi(vh), a3);      \
    }

    // phase A: gather 4 nodes per wave, paired rows, 8 edges in flight
    for (int j = 0; j < 4; ++j) {
        int row = wv4 + j;
        int node = nbase + row;
        float a0 = 0.f, a1 = 0.f, a2 = 0.f, a3 = 0.f;
        if (node < N) {
            int nu = __builtin_amdgcn_readfirstlane(node);
            int e0 = rp[nu], e1 = rp[nu + 1];
            float di = dinv[nu];
            float dd = di * di;
            u64 mself = ((u64)__float_as_uint(dd) << 32) | (uint)(nu << 8);
            u64 mzero = (u64)(uint)(nu << 8);           // weight 0
            int ep = e0;
            if (ep < e1) {
                u64 p = LD64(ep); ++ep;
                PAIRF(mself, p);
            } else {
                PAIRF(mself, mzero);
            }
            if (ep + 8 <= e1) {
                u64 m0 = LD64(ep), m1 = LD64(ep + 1), m2 = LD64(ep + 2), m3 = LD64(ep + 3),
                    m4 = LD64(ep + 4), m5 = LD64(ep + 5), m6 = LD64(ep + 6), m7 = LD64(ep + 7);
                ep += 8;
                for (; ep + 8 <= e1; ep += 8) {
                    uint o0 = lowh ? (uint)m0 : (uint)m1;
                    uint o1 = lowh ? (uint)m2 : (uint)m3;
                    uint o2 = lowh ? (uint)m4 : (uint)m5;
                    uint o3 = lowh ? (uint)m6 : (uint)m7;
                    u64 v0 = *(const u64*)(tlb + o0);
                    u64 v1 = *(const u64*)(tlb + o1);
                    u64 v2 = *(const u64*)(tlb + o2);
                    u64 v3 = *(const u64*)(tlb + o3);
                    u64 t0 = LD64(ep), t1 = LD64(ep + 1), t2 = LD64(ep + 2), t3 = LD64(ep + 3),
                        t4 = LD64(ep + 4), t5 = LD64(ep + 5), t6 = LD64(ep + 6), t7 = LD64(ep + 7);
                    GFMA(m0, m1, v0); GFMA(m2, m3, v1);
                    GFMA(m4, m5, v2); GFMA(m6, m7, v3);
                    m0 = t0; m1 = t1; m2 = t2; m3 = t3;
                    m4 = t4; m5 = t5; m6 = t6; m7 = t7;
                }
                {   // drain
                    uint o0 = lowh ? (uint)m0 : (uint)m1;
                    uint o1 = lowh ? (uint)m2 : (uint)m3;
                    uint o2 = lowh ? (uint)m4 : (uint)m5;
                    uint o3 = lowh ? (uint)m6 : (uint)m7;
                    u64 v0 = *(const u64*)(tlb + o0);
                    u64 v1 = *(const u64*)(tlb + o1);
                    u64 v2 = *(const u64*)(tlb + o2);
                    u64 v3 = *(const u64*)(tlb + o3);
                    GFMA(m0, m1, v0); GFMA(m2, m3, v1);
                    GFMA(m4, m5, v2); GFMA(m6, m7, v3);
                }
            }
            for (; ep + 2 <= e1; ep += 2) {
                u64 pa = LD64(ep), pb = LD64(ep + 1);
                PAIRF(pa, pb);
            }
            if (ep < e1) {
                u64 pa = LD64(ep);
                PAIRF(pa, mzero);
            }
            a0 += __shfl_xor(a0, 32); a1 += __shfl_xor(a1, 32);
            a2 += __shfl_xor(a2, 32); a3 += __shfl_xor(a3, 32);
        }
        if (lane < 32) {
            uint2 o;
            o.x = pack2(a0, a1);
            o.y = pack2(a2, a3);
            *(uint2*)(Asw + row * 256 + ((lane * 8) ^ ((row & 7) << 4))) = o;
        }
    }
    __syncthreads();

    // phase B: 16x128 @ 128x128 MFMA — wave wv computes n-tiles {2wv, 2wv+1}
    int m = lane & 15, g = lane >> 4;
    bf16x8 a[4];
    int aswz = (m & 7) << 4;
#pragma unroll
    for (int kk = 0; kk < 4; ++kk)
        a[kk] = *(const bf16x8*)(Asw + m * 256 + ((kk * 64 + g * 16) ^ aswz));

    f32x4 acc[2];
    acc[0] = (f32x4){0.f, 0.f, 0.f, 0.f};
    acc[1] = (f32x4){0.f, 0.f, 0.f, 0.f};
#pragma unroll
    for (int t2 = 0; t2 < 2; ++t2) {
        int n = m + (2 * wv + t2) * 16;
        const char* wb = (const char*)Wp + (n << 8);
        int swz = (n & 7) << 4;
#pragma unroll
        for (int kk = 0; kk < 4; ++kk) {
            bf16x8 b = *(const bf16x8*)(wb + ((kk * 64 + g * 16) ^ swz));
            acc[t2] = __builtin_amdgcn_mfma_f32_16x16x32_bf16(a[kk], b, acc[t2], 0, 0, 0);
        }
    }

    // bias + relu, per-row partial sums
    float bc0 = bias[m + (2 * wv) * 16];
    float bc1 = bias[m + (2 * wv + 1) * 16];
    float vals0[4], vals1[4];
#pragma unroll
    for (int q = 0; q < 4; ++q) {
        float v0 = fmaxf(acc[0][q] + bc0, 0.f);
        float v1 = fmaxf(acc[1][q] + bc1, 0.f);
        vals0[q] = v0; vals1[q] = v1;
        float s1 = v0 + v1, s2 = v0 * v0 + v1 * v1;
#pragma unroll
        for (int off = 1; off < 16; off <<= 1) { s1 += __shfl_xor(s1, off); s2 += __shfl_xor(s2, off); }
        if (m == 0) {
            red[(g * 4 + q) * 4 + wv] = s1;
            red[64 + (g * 4 + q) * 4 + wv] = s2;
        }
    }
    __syncthreads();

    // phase C: LN -> bf16 staging
    float gc0 = gamma[m + (2 * wv) * 16],  gc1 = gamma[m + (2 * wv + 1) * 16];
    float be0 = beta[m + (2 * wv) * 16],   be1 = beta[m + (2 * wv + 1) * 16];
#pragma unroll
    for (int q = 0; q < 4; ++q) {
        int row = g * 4 + q;
        float s1 = red[row * 4] + red[row * 4 + 1] + red[row * 4 + 2] + red[row * 4 + 3];
        float s2 = red[64 + row * 4] + red[64 + row * 4 + 1] + red[64 + row * 4 + 2] + red[64 + row * 4 + 3];
        float mu = s1 * (1.f / 128.f), var = s2 * (1.f / 128.f) - mu * mu;
        float r = rsqrtf(var + EPSV);
        ((ushort*)Cst)[row * 128 + m + (2 * wv) * 16]     = (ushort)bf16_rne((vals0[q] - mu) * r * gc0 + be0);
        ((ushort*)Cst)[row * 128 + m + (2 * wv + 1) * 16] = (ushort)bf16_rne((vals1[q] - mu) * r * gc1 + be1);
    }
    __syncthreads();

    if (outp) {
#pragma unroll
        for (int rr = 0; rr < 4; ++rr) {
            int row = rr * 4 + wv;
            int node = nbase + row;
            if (node < N)
                outp[(size_t)node * 64 + lane] = Cst[row * 64 + lane];
        }
    }
    if (featsum) {
        if (tid < 16) {
            int node = nbase + tid;
            bi[tid] = (node < N) ? batch[node] : -1;
        }
        __syncthreads();
        int gmin = 0x7fffffff, gmax = -1;
#pragma unroll
        for (int r2 = 0; r2 < 16; ++r2) {
            int b = bi[r2];
            if (b >= 0) { gmin = min(gmin, b); gmax = max(gmax, b); }
        }
        if (tid < 128 && gmax >= 0) {
            for (int gg = gmin; gg <= gmax; ++gg) {
                float sv = 0.f; int cnt = 0;
#pragma unroll
                for (int r2 = 0; r2 < 16; ++r2) {
                    if (bi[r2] == gg) {
                        uint u = Cst[r2 * 64 + (tid >> 1)];
                        sv += (tid & 1) ? bhi(u) : blo(u);
                        cnt++;
                    }
                }
                if (cnt) atomicAdd(&featsum[gg * 128 + tid], sv);
            }
        }
    }
#undef WTF
#undef LD64
#undef PAIRF
#undef GFMA
}

// ---------------- fused FC head, 1024 threads ----------------

__global__ void __launch_bounds__(1024) k_fc(const float* __restrict__ featsum,
        const int* __restrict__ batch, int N,
        const float* __restrict__ W1, const float* __restrict__ b1,
        const float* __restrict__ W2, const float* __restrict__ b2,
        const float* __restrict__ W3, const float* __restrict__ b3,
        float* __restrict__ out) {
    int g = blockIdx.x, tid = threadIdx.x;
    int wv = tid >> 6, lane = tid & 63;
    __shared__ float fr[128];
    __shared__ float z1s[1024];
    __shared__ float z2p[1024];
    __shared__ float z2s[256];
    __shared__ float red[32];
    __shared__ float red2[64];
    __shared__ int cnts;
    if (tid == 0) {
        int lo = 0, hi = N;
        while (lo < hi) { int mm = (lo + hi) >> 1; if (batch[mm] < g) lo = mm + 1; else hi = mm; }
        int st = lo; hi = N;
        while (lo < hi) { int mm = (lo + hi) >> 1; if (batch[mm] < g + 1) lo = mm + 1; else hi = mm; }
        cnts = lo - st;
    }
    __syncthreads();
    float inv = 1.f / fmaxf((float)cnts, 1.f);
    if (tid < 128) fr[tid] = featsum[g * 128 + tid] * inv;
    __syncthreads();

    // fc1: 1024 outputs, 1/thread, k=128
    float a1 = b1[tid];
#pragma unroll 8
    for (int k = 0; k < 128; ++k) a1 = fmaf(fr[k], W1[k * 1024 + tid], a1);
    float s1 = a1, s2 = a1 * a1;
#pragma unroll
    for (int off = 1; off < 64; off <<= 1) { s1 += __shfl_xor(s1, off); s2 += __shfl_xor(s2, off); }
    if (lane == 0) { red[wv] = s1; red[16 + wv] = s2; }
    __syncthreads();
    float t1 = 0.f, t2 = 0.f;
#pragma unroll
    for (int i = 0; i < 16; ++i) { t1 += red[i]; t2 += red[16 + i]; }
    float mu = t1 * (1.f / 1024.f), var = t2 * (1.f / 1024.f) - mu * mu;
    float r = rsqrtf(var + EPSV);
    z1s[tid] = fmaxf((a1 - mu) * r, 0.f);
    __syncthreads();

    // fc2: out = tid&255, k-slice = tid>>8 (256 k's each)
    int o2 = tid & 255, ks = tid >> 8;
    float a2 = (ks == 0) ? b2[o2] : 0.f;
    int kb = ks * 256;
#pragma unroll 8
    for (int k = 0; k < 256; ++k) a2 = fmaf(z1s[kb + k], W2[(kb + k) * 256 + o2], a2);
    z2p[tid] = a2;
    __syncthreads();

    float v2 = 0.f;
    if (tid < 256) {
        v2 = z2p[tid] + z2p[256 + tid] + z2p[512 + tid] + z2p[768 + tid];
        s1 = v2; s2 = v2 * v2;
#pragma unroll
        for (int off = 1; off < 64; off <<= 1) { s1 += __shfl_xor(s1, off); s2 += __shfl_xor(s2, off); }
        if (lane == 0) { red[wv] = s1; red[16 + wv] = s2; }
    }
    __syncthreads();
    if (tid < 256) {
        t1 = red[0] + red[1] + red[2] + red[3];
        t2 = red[16] + red[17] + red[18] + red[19];
        mu = t1 * (1.f / 256.f); var = t2 * (1.f / 256.f) - mu * mu;
        r = rsqrtf(var + EPSV);
        z2s[tid] = fmaxf((v2 - mu) * r, 0.f);
    }
    __syncthreads();

    // fc3: thread = (k = tid>>2, o = tid&3); W3[tid] coalesced
    {
        float p = z2s[tid >> 2] * W3[tid];
#pragma unroll
        for (int off = 4; off < 64; off <<= 1) p += __shfl_xor(p, off);
        if ((lane & 63) < 4) red2[wv * 4 + (lane & 3)] = p;
    }
    __syncthreads();
    if (tid < 4) {
        float a3 = b3[tid];
#pragma unroll
        for (int i = 0; i < 16; ++i) a3 += red2[i * 4 + tid];
        out[g * 4 + tid] = a3;
    }
}

// ---------------- launch ----------------

extern "C" void kernel_launch(void* const* d_in, const int* in_sizes, int n_in,
                              void* d_out, int out_size, void* d_ws, size_t ws_size,
                              hipStream_t stream) {
    const float* x    = (const float*)d_in[0];
    const int*   ei   = (const int*)d_in[1];
    const int*   batch= (const int*)d_in[2];
    const float* Wl[4]  = { (const float*)d_in[3], (const float*)d_in[7],  (const float*)d_in[11], (const float*)d_in[15] };
    const float* bl[4]  = { (const float*)d_in[4], (const float*)d_in[8],  (const float*)d_in[12], (const float*)d_in[16] };
    const float* gl[4]  = { (const float*)d_in[5], (const float*)d_in[9],  (const float*)d_in[13], (const float*)d_in[17] };
    const float* bel[4] = { (const float*)d_in[6], (const float*)d_in[10], (const float*)d_in[14], (const float*)d_in[18] };
    const float* fcW1 = (const float*)d_in[19];
    const float* fcb1 = (const float*)d_in[20];
    const float* fcW2 = (const float*)d_in[21];
    const float* fcb2 = (const float*)d_in[22];
    const float* fcW3 = (const float*)d_in[23];
    const float* fcb3 = (const float*)d_in[24];
    float* out = (float*)d_out;

    const int N = in_sizes[2];
    const int E = in_sizes[1] / 2;

    char* w = (char*)d_ws;
    auto alloc = [&](size_t bytes) -> char* {
        char* p = w; w += (bytes + 255) & ~(size_t)255; return p;
    };
    uint*   hA      = (uint*)  alloc((size_t)N * 64 * 4);   // bf16 N x 128
    uint*   hB      = (uint*)  alloc((size_t)N * 64 * 4);
    int2*   edata   = (int2*)  alloc((size_t)E * 8);
    int*    seq     = (int*)   alloc((size_t)E * 4);
    int*    rp      = (int*)   alloc((size_t)(N + 1) * 4);
    int*    cntI    = (int*)   alloc((size_t)N * 4);
    float*  dinv    = (float*) alloc((size_t)N * 4);
    int*    partial = (int*)   alloc(64 * 4);
    ushort* Wp      = (ushort*)alloc(3 * 128 * 128 * 2);
    float*  featsum = (float*) alloc(NGRAPH * HIDC * 4);

    const int NCH = (N + 2047) / 2048;
    int egrid4 = (E / 4 + 256) / 256;
    int ngrid = (N + 255) / 256;

    k_init<<<ngrid + 3, 256, 0, stream>>>(cntI, featsum, N, Wl[1], Wl[2], Wl[3], Wp, ngrid);
    k_count<<<egrid4, 256, 0, stream>>>(ei, E, cntI, seq);
    k_scan1<<<NCH, 256, 0, stream>>>(cntI, rp, partial, N);
    k_scan3<<<ngrid, 256, 0, stream>>>(rp, partial, cntI, dinv, N, E, NCH);
    k_fill<<<egrid4, 256, 0, stream>>>(ei, E, dinv, rp, seq, edata);

    // layer 0 fused -> hA
    k_l0<<<(N + 15) / 16, 256, 0, stream>>>(x, edata, rp, dinv, Wl[0], bl[0], gl[0], bel[0], hA, N);

    // layers 1..3 fused; layer 3 pools (no table write)
    const int fgrid = (N + 15) / 16;
    k_aggw<<<fgrid, 256, 0, stream>>>(hA, edata, rp, dinv, Wp + 0 * 128 * 128,
                                      bl[1], gl[1], bel[1], hB, N, nullptr, batch);
    k_aggw<<<fgrid, 256, 0, stream>>>(hB, edata, rp, dinv, Wp + 1 * 128 * 128,
                                      bl[2], gl[2], bel[2], hA, N, nullptr, batch);
    k_aggw<<<fgrid, 256, 0, stream>>>(hA, edata, rp, dinv, Wp + 2 * 128 * 128,
                                      bl[3], gl[3], bel[3], nullptr, N, featsum, batch);

    k_fc<<<NGRAPH, 1024, 0, stream>>>(featsum, batch, N, fcW1, fcb1, fcW2, fcb2, fcW3, fcb3, out);
}